// Round 1
// baseline (1059.358 us; speedup 1.0000x reference)
//
#include <hip/hip_runtime.h>
#include <hip/hip_bf16.h>

// Problem dims
#define PP 512
#define QQ 64
#define BB 16
#define EE 256
#define HH 256
#define OO 256

typedef _Float16 half2_t __attribute__((ext_vector_type(2)));

__device__ __forceinline__ void unpack8h(const uint4 r, float* v) {
    const _Float16* s = (const _Float16*)&r;
#pragma unroll
    for (int i = 0; i < 8; i++) v[i] = (float)s[i];
}
__device__ __forceinline__ float fast_tanh(float x) {
    x = fminf(fmaxf(x, -15.f), 15.f);
    float e = __expf(2.f * x);
    return (e - 1.f) * __frcp_rn(e + 1.f);
}
__device__ __forceinline__ float fast_sigmoid(float x) {
    x = fminf(fmaxf(x, -30.f), 30.f);
    return __frcp_rn(1.f + __expf(-x));
}
__device__ __forceinline__ float fdot2f(half2_t a, half2_t b, float c) {
#if defined(__has_builtin)
#if __has_builtin(__builtin_amdgcn_fdot2)
    return __builtin_amdgcn_fdot2(a, b, c, false);
#else
    return (float)a[0] * (float)b[0] + (float)a[1] * (float)b[1] + c;
#endif
#else
    return (float)a[0] * (float)b[0] + (float)a[1] * (float)b[1] + c;
#endif
}

// ---------------------------------------------------------------------------
// Generic tiled GEMM: C[m,n] = epilogue( sum_k A[m,k] * B[n,k] )
// Tile 128x128, K-chunk 16, 256 threads, 8x8 micro-tile, fp32 accumulate.
// Output fp16. B (weight) is fp32, row n = B[n, 0:K].
// AMODE: 0 = A fp32 (row stride K)
//        2 = A concat: k<256 -> Af32 (fp32, row stride 256), k>=256 -> Ah (f16, row stride 256)
//        3 = A f16 (row stride K)
// EPI:   0 = none
//        1 = + bias[n] (fp32)
//        2 = sigmoid(acc) * gateC[m*256+n] (f16)   [only used with N=256]
// ---------------------------------------------------------------------------
template <int AMODE, int EPI>
__global__ __launch_bounds__(256) void gemm_k(
    const float* __restrict__ Af32,
    const _Float16* __restrict__ Ah,
    const float* __restrict__ Bw,
    const float* __restrict__ bias,
    const _Float16* __restrict__ gateC,
    _Float16* __restrict__ Cout, int M, int N, int K)
{
    __shared__ float As[16][128];
    __shared__ float Bs[16][128];
    const int tid = threadIdx.x;
    const int bm = blockIdx.x, bn = blockIdx.y;
    const int ra = tid >> 1;          // 0..127 : row within tile for staging
    const int ka = (tid & 1) * 8;     // 0 or 8 : k-offset within chunk
    const int tm = (tid >> 4) * 8;    // micro-tile row base
    const int tn = (tid & 15) * 8;    // micro-tile col base

    float acc[8][8];
#pragma unroll
    for (int i = 0; i < 8; i++)
#pragma unroll
        for (int j = 0; j < 8; j++) acc[i][j] = 0.f;

    const long arow = (long)bm * 128 + ra;
    const long brow = (long)bn * 128 + ra;

    for (int k0 = 0; k0 < K; k0 += 16) {
        float av[8], bv[8];
        const int kk = k0 + ka;
        if (AMODE == 0) {
            const float* p = Af32 + arow * K + kk;
            float4 r0 = *(const float4*)(p);
            float4 r1 = *(const float4*)(p + 4);
            av[0] = r0.x; av[1] = r0.y; av[2] = r0.z; av[3] = r0.w;
            av[4] = r1.x; av[5] = r1.y; av[6] = r1.z; av[7] = r1.w;
        } else if (AMODE == 3) {
            uint4 r = *(const uint4*)(Ah + arow * K + kk);
            unpack8h(r, av);
        } else { // AMODE == 2
            if (kk < 256) {
                const float* p = Af32 + arow * 256 + kk;
                float4 r0 = *(const float4*)(p);
                float4 r1 = *(const float4*)(p + 4);
                av[0] = r0.x; av[1] = r0.y; av[2] = r0.z; av[3] = r0.w;
                av[4] = r1.x; av[5] = r1.y; av[6] = r1.z; av[7] = r1.w;
            } else {
                uint4 r = *(const uint4*)(Ah + arow * 256 + (kk - 256));
                unpack8h(r, av);
            }
        }
        {
            const float* p = Bw + brow * K + kk;
            float4 r0 = *(const float4*)(p);
            float4 r1 = *(const float4*)(p + 4);
            bv[0] = r0.x; bv[1] = r0.y; bv[2] = r0.z; bv[3] = r0.w;
            bv[4] = r1.x; bv[5] = r1.y; bv[6] = r1.z; bv[7] = r1.w;
        }
        __syncthreads();
#pragma unroll
        for (int i = 0; i < 8; i++) { As[ka + i][ra] = av[i]; Bs[ka + i][ra] = bv[i]; }
        __syncthreads();
#pragma unroll
        for (int k = 0; k < 16; k++) {
            float a[8], b[8];
            *(float4*)&a[0] = *(const float4*)&As[k][tm];
            *(float4*)&a[4] = *(const float4*)&As[k][tm + 4];
            *(float4*)&b[0] = *(const float4*)&Bs[k][tn];
            *(float4*)&b[4] = *(const float4*)&Bs[k][tn + 4];
#pragma unroll
            for (int i = 0; i < 8; i++)
#pragma unroll
                for (int j = 0; j < 8; j++)
                    acc[i][j] = fmaf(a[i], b[j], acc[i][j]);
        }
    }

#pragma unroll
    for (int i = 0; i < 8; i++) {
        const long m = (long)bm * 128 + tm + i;
#pragma unroll
        for (int j = 0; j < 8; j++) {
            const int n = bn * 128 + tn + j;
            float v = acc[i][j];
            if (EPI == 1) v += bias[n];
            if (EPI == 2) v = fast_sigmoid(v) * (float)gateC[m * 256 + n];
            Cout[m * (long)N + n] = (_Float16)v;
        }
    }
}

// ---------------------------------------------------------------------------
// Fused attention: per block = one (p,b) pair (m = p*16+b).
// ---------------------------------------------------------------------------
__global__ __launch_bounds__(256) void attn_k(
    const float* __restrict__ question,  // (Q,B,E) fp32
    const float* __restrict__ vvec,      // (H,) fp32
    const _Float16* __restrict__ Wp,     // (P*B, H) f16
    const _Float16* __restrict__ Wq,     // (Q*B, H) f16
    _Float16* __restrict__ Cc)           // (P*B, E) f16 out
{
    __shared__ float sc[QQ];
    __shared__ float aw[QQ];
    const int tid = threadIdx.x;
    const int blk = blockIdx.x;   // m = p*16 + b
    const int b = blk & 15;
    const int wave = tid >> 6, lane = tid & 63;

    float wp0[4], vv[4];
#pragma unroll
    for (int j = 0; j < 4; j++) {
        wp0[j] = (float)Wp[(long)blk * 256 + lane + 64 * j];
        vv[j] = vvec[lane + 64 * j];
    }
#pragma unroll 2
    for (int qi = 0; qi < 16; qi++) {
        const int q = wave * 16 + qi;
        const _Float16* wqp = Wq + (long)(q * 16 + b) * 256;
        float s = 0.f;
#pragma unroll
        for (int j = 0; j < 4; j++) {
            float x = (float)wqp[lane + 64 * j] + wp0[j];
            s += fast_tanh(x) * vv[j];
        }
#pragma unroll
        for (int off = 32; off; off >>= 1) s += __shfl_xor(s, off, 64);
        if (lane == 0) sc[q] = s;
    }
    __syncthreads();
    if (tid < 64) {
        float s = sc[tid];
        float mx = s;
#pragma unroll
        for (int off = 32; off; off >>= 1) mx = fmaxf(mx, __shfl_xor(mx, off, 64));
        float e = __expf(s - mx);
        float sum = e;
#pragma unroll
        for (int off = 32; off; off >>= 1) sum += __shfl_xor(sum, off, 64);
        aw[tid] = e * __frcp_rn(sum);
    }
    __syncthreads();
    float acc = 0.f;
#pragma unroll 4
    for (int q = 0; q < QQ; q++) {
        acc = fmaf(aw[q], question[(long)(q * 16 + b) * 256 + tid], acc);
    }
    Cc[(long)blk * 256 + tid] = (_Float16)acc;
}

// ---------------------------------------------------------------------------
// GRU scan, v3. 16 blocks (one per batch b), 1024 threads (16 waves, 4/SIMD).
// Decomposition: thread (q, e), q = tid>>8 in 0..3, e = tid&255.
// Thread computes, for h-element e, the quarter-dot over k in [64q, 64q+64)
// of all three gate rows {e, e+256, e+512} of w_hh, held in VGPRs as fp16
// pairs: 3 x 32 half2 = 96 VGPRs (fits the 128-VGPR budget a 16-wave block
// requires -> no AGPR round-trips in the hot loop, unlike the 512-thread
// half-split whose 192 weight regs overflowed the 128-VGPR allocation).
// q=1..3 write their 3 partials to LDS; q=0 combines, applies gates, owns
// h[e] (fp32 in register), writes f16 h to the double-buffered broadcast
// buffer. Two barriers per step. h broadcast reads are same-address wave
// broadcasts (each wave spans exactly one q-group) -> conflict-free.
// ---------------------------------------------------------------------------
__global__ __launch_bounds__(1024) void gru_k(
    const float* __restrict__ whh,    // (768,256) fp32
    const float* __restrict__ bhh,    // (768,) fp32
    const _Float16* __restrict__ gi,  // (P*B, 768) f16 (b_ih folded in)
    float* __restrict__ out)          // (P,B,O) fp32
{
    __shared__ __align__(16) _Float16 hbuf[2][256];
    __shared__ float part[3][3][256];   // [q-1][gate][e]
    const int tid = threadIdx.x;
    const int q = tid >> 8;       // k-slice index 0..3
    const int e = tid & 255;
    const int b = blockIdx.x;
    const int koff = q * 64;

    // Load weight slices: rows e (r-gate), e+256 (z), e+512 (n), cols [koff, koff+64)
    half2_t wr[32], wz[32], wn[32];
    {
        const float* pr = whh + (long)e * 256 + koff;
        const float* pz = whh + (long)(e + 256) * 256 + koff;
        const float* pn = whh + (long)(e + 512) * 256 + koff;
#pragma unroll
        for (int j = 0; j < 16; j++) {
            float4 a = *(const float4*)(pr + 4 * j);
            float4 c = *(const float4*)(pz + 4 * j);
            float4 d = *(const float4*)(pn + 4 * j);
            half2_t t;
            t[0] = (_Float16)a.x; t[1] = (_Float16)a.y; wr[2 * j] = t;
            t[0] = (_Float16)a.z; t[1] = (_Float16)a.w; wr[2 * j + 1] = t;
            t[0] = (_Float16)c.x; t[1] = (_Float16)c.y; wz[2 * j] = t;
            t[0] = (_Float16)c.z; t[1] = (_Float16)c.w; wz[2 * j + 1] = t;
            t[0] = (_Float16)d.x; t[1] = (_Float16)d.y; wn[2 * j] = t;
            t[0] = (_Float16)d.z; t[1] = (_Float16)d.w; wn[2 * j + 1] = t;
        }
    }
    float b_r = 0.f, b_z = 0.f, b_n = 0.f;
    if (q == 0) {
        b_r = bhh[e];
        b_z = bhh[e + 256];
        b_n = bhh[e + 512];
        hbuf[0][e] = (_Float16)0.f;
    }
    float h = 0.f;
    __syncthreads();

    int cur = 0;
    for (int t = 0; t < PP; t++) {
        // gi prefetch (q==0 only); latency hidden by the matvec + barrier.
        float g0 = 0.f, g1 = 0.f, g2 = 0.f;
        if (q == 0) {
            const _Float16* gip = gi + ((long)t * 16 + b) * 768;
            g0 = (float)gip[e];
            g1 = (float)gip[e + 256];
            g2 = (float)gip[e + 512];
        }
        // Quarter-dot over this thread's 64-wide k-slice of the broadcast h.
        const uint4* hp4 = ((const uint4*)hbuf[cur]) + q * 8;
        float ar = 0.f, az = 0.f, an = 0.f;
#pragma unroll
        for (int j = 0; j < 8; j++) {
            uint4 hp = hp4[j];
            half2_t h0 = __builtin_bit_cast(half2_t, hp.x);
            half2_t h1 = __builtin_bit_cast(half2_t, hp.y);
            half2_t h2 = __builtin_bit_cast(half2_t, hp.z);
            half2_t h3 = __builtin_bit_cast(half2_t, hp.w);
            ar = fdot2f(wr[4 * j + 0], h0, ar);
            ar = fdot2f(wr[4 * j + 1], h1, ar);
            ar = fdot2f(wr[4 * j + 2], h2, ar);
            ar = fdot2f(wr[4 * j + 3], h3, ar);
            az = fdot2f(wz[4 * j + 0], h0, az);
            az = fdot2f(wz[4 * j + 1], h1, az);
            az = fdot2f(wz[4 * j + 2], h2, az);
            az = fdot2f(wz[4 * j + 3], h3, az);
            an = fdot2f(wn[4 * j + 0], h0, an);
            an = fdot2f(wn[4 * j + 1], h1, an);
            an = fdot2f(wn[4 * j + 2], h2, an);
            an = fdot2f(wn[4 * j + 3], h3, an);
        }
        if (q) {
            part[q - 1][0][e] = ar;
            part[q - 1][1][e] = az;
            part[q - 1][2][e] = an;
        }
        __syncthreads();
        if (q == 0) {
            float ghr = ar + part[0][0][e] + part[1][0][e] + part[2][0][e] + b_r;
            float ghz = az + part[0][1][e] + part[1][1][e] + part[2][1][e] + b_z;
            float ghn = an + part[0][2][e] + part[1][2][e] + part[2][2][e] + b_n;
            float r = fast_sigmoid(g0 + ghr);
            float z = fast_sigmoid(g1 + ghz);
            float n = fast_tanh(fmaf(r, ghn, g2));
            h = (1.f - z) * n + z * h;
            out[((long)t * 16 + b) * 256 + e] = h;
            hbuf[cur ^ 1][e] = (_Float16)h;
        }
        __syncthreads();
        cur ^= 1;
    }
}

// ---------------------------------------------------------------------------
extern "C" void kernel_launch(void* const* d_in, const int* in_sizes, int n_in,
                              void* d_out, int out_size, void* d_ws, size_t ws_size,
                              hipStream_t stream)
{
    const float* passage  = (const float*)d_in[0];   // (512,16,256) fp32
    const float* question = (const float*)d_in[1];   // (64,16,256) fp32
    const float* Wuq      = (const float*)d_in[2];   // (256,256) fp32
    const float* Wup      = (const float*)d_in[3];   // (256,256) fp32
    const float* vvec     = (const float*)d_in[4];   // (1,256) fp32
    const float* Wg       = (const float*)d_in[5];   // (512,512) fp32
    const float* w_ih     = (const float*)d_in[6];   // (768,256) fp32
    const float* w_hh     = (const float*)d_in[7];   // (768,256) fp32
    const float* b_ih     = (const float*)d_in[8];   // (768,) fp32
    const float* b_hh     = (const float*)d_in[9];   // (768,) fp32

    // Workspace layout (all fp16) — total footprint exactly 16 MiB.
    //   [0,      12.0MiB) : gi (8192x768)  — written LAST; overlaps Wq/Wp/c,
    //                        which are all dead by the time gi is produced.
    //       [0,     0.5MiB) : Wq (1024x256)   dead after attn
    //       [0.5,   4.5MiB) : Wp (8192x256)   dead after attn
    //       [4.5,   8.5MiB) : c  (8192x256)   dead after gate GEMM
    //   [12MiB, 16MiB)     : cg (8192x256)    alive until gi GEMM done
    char* ws = (char*)d_ws;
    _Float16* gi_ws = (_Float16*)(ws);
    _Float16* Wq_ws = (_Float16*)(ws);
    _Float16* Wp_ws = (_Float16*)(ws + (512u << 10));
    _Float16* c_ws  = (_Float16*)(ws + (4608u << 10));
    _Float16* cg_ws = (_Float16*)(ws + (12288u << 10));

    // 1) Wq = question @ Wuq^T   (1024 x 256, K=256)
    gemm_k<0, 0><<<dim3(8, 2), 256, 0, stream>>>(question, nullptr, Wuq, nullptr, nullptr,
                                                 Wq_ws, 1024, 256, 256);
    // 2) Wp = passage @ Wup^T    (8192 x 256, K=256)
    gemm_k<0, 0><<<dim3(64, 2), 256, 0, stream>>>(passage, nullptr, Wup, nullptr, nullptr,
                                                  Wp_ws, 8192, 256, 256);
    // 3) attention -> c (8192 x 256)
    attn_k<<<8192, 256, 0, stream>>>(question, vvec, Wp_ws, Wq_ws, c_ws);
    // 4) cg = sigmoid([passage,c] @ Wg[256:512]^T) * c   (8192 x 256, K=512)
    gemm_k<2, 2><<<dim3(64, 2), 256, 0, stream>>>(passage, c_ws, Wg + 256 * 512, nullptr, c_ws,
                                                  cg_ws, 8192, 256, 512);
    // 5) gi = cg @ w_ih^T + b_ih   (8192 x 768, K=256)
    gemm_k<3, 1><<<dim3(64, 6), 256, 0, stream>>>(nullptr, cg_ws, w_ih, b_ih, nullptr,
                                                  gi_ws, 8192, 768, 256);
    // 6) GRU scan -> out (fp32)
    gru_k<<<16, 1024, 0, stream>>>(w_hh, b_hh, gi_ws, (float*)d_out);
}

// Round 2
// 1053.584 us; speedup vs baseline: 1.0055x; 1.0055x over previous
//
#include <hip/hip_runtime.h>
#include <hip/hip_bf16.h>

// Problem dims
#define PP 512
#define QQ 64
#define BB 16
#define EE 256
#define HH 256
#define OO 256

typedef _Float16 half2_t __attribute__((ext_vector_type(2)));

__device__ __forceinline__ void unpack8h(const uint4 r, float* v) {
    const _Float16* s = (const _Float16*)&r;
#pragma unroll
    for (int i = 0; i < 8; i++) v[i] = (float)s[i];
}
__device__ __forceinline__ float fast_tanh(float x) {
    x = fminf(fmaxf(x, -15.f), 15.f);
    float e = __expf(2.f * x);
    return (e - 1.f) * __frcp_rn(e + 1.f);
}
__device__ __forceinline__ float fast_sigmoid(float x) {
    x = fminf(fmaxf(x, -30.f), 30.f);
    return __frcp_rn(1.f + __expf(-x));
}
__device__ __forceinline__ float fdot2f(half2_t a, half2_t b, float c) {
#if defined(__has_builtin)
#if __has_builtin(__builtin_amdgcn_fdot2)
    return __builtin_amdgcn_fdot2(a, b, c, false);
#else
    return (float)a[0] * (float)b[0] + (float)a[1] * (float)b[1] + c;
#endif
#else
    return (float)a[0] * (float)b[0] + (float)a[1] * (float)b[1] + c;
#endif
}

// ---------------------------------------------------------------------------
// Generic tiled GEMM: C[m,n] = epilogue( sum_k A[m,k] * B[n,k] )
// Tile 128x128, K-chunk 16, 256 threads, 8x8 micro-tile, fp32 accumulate.
// Output fp16. B (weight) is fp32, row n = B[n, 0:K].
// AMODE: 0 = A fp32 (row stride K)
//        2 = A concat: k<256 -> Af32 (fp32, row stride 256), k>=256 -> Ah (f16, row stride 256)
//        3 = A f16 (row stride K)
// EPI:   0 = none
//        1 = + bias[n] (fp32)
//        2 = sigmoid(acc) * gateC[m*256+n] (f16)   [only used with N=256]
// ---------------------------------------------------------------------------
template <int AMODE, int EPI>
__global__ __launch_bounds__(256) void gemm_k(
    const float* __restrict__ Af32,
    const _Float16* __restrict__ Ah,
    const float* __restrict__ Bw,
    const float* __restrict__ bias,
    const _Float16* __restrict__ gateC,
    _Float16* __restrict__ Cout, int M, int N, int K)
{
    __shared__ float As[16][128];
    __shared__ float Bs[16][128];
    const int tid = threadIdx.x;
    const int bm = blockIdx.x, bn = blockIdx.y;
    const int ra = tid >> 1;          // 0..127 : row within tile for staging
    const int ka = (tid & 1) * 8;     // 0 or 8 : k-offset within chunk
    const int tm = (tid >> 4) * 8;    // micro-tile row base
    const int tn = (tid & 15) * 8;    // micro-tile col base

    float acc[8][8];
#pragma unroll
    for (int i = 0; i < 8; i++)
#pragma unroll
        for (int j = 0; j < 8; j++) acc[i][j] = 0.f;

    const long arow = (long)bm * 128 + ra;
    const long brow = (long)bn * 128 + ra;

    for (int k0 = 0; k0 < K; k0 += 16) {
        float av[8], bv[8];
        const int kk = k0 + ka;
        if (AMODE == 0) {
            const float* p = Af32 + arow * K + kk;
            float4 r0 = *(const float4*)(p);
            float4 r1 = *(const float4*)(p + 4);
            av[0] = r0.x; av[1] = r0.y; av[2] = r0.z; av[3] = r0.w;
            av[4] = r1.x; av[5] = r1.y; av[6] = r1.z; av[7] = r1.w;
        } else if (AMODE == 3) {
            uint4 r = *(const uint4*)(Ah + arow * K + kk);
            unpack8h(r, av);
        } else { // AMODE == 2
            if (kk < 256) {
                const float* p = Af32 + arow * 256 + kk;
                float4 r0 = *(const float4*)(p);
                float4 r1 = *(const float4*)(p + 4);
                av[0] = r0.x; av[1] = r0.y; av[2] = r0.z; av[3] = r0.w;
                av[4] = r1.x; av[5] = r1.y; av[6] = r1.z; av[7] = r1.w;
            } else {
                uint4 r = *(const uint4*)(Ah + arow * 256 + (kk - 256));
                unpack8h(r, av);
            }
        }
        {
            const float* p = Bw + brow * K + kk;
            float4 r0 = *(const float4*)(p);
            float4 r1 = *(const float4*)(p + 4);
            bv[0] = r0.x; bv[1] = r0.y; bv[2] = r0.z; bv[3] = r0.w;
            bv[4] = r1.x; bv[5] = r1.y; bv[6] = r1.z; bv[7] = r1.w;
        }
        __syncthreads();
#pragma unroll
        for (int i = 0; i < 8; i++) { As[ka + i][ra] = av[i]; Bs[ka + i][ra] = bv[i]; }
        __syncthreads();
#pragma unroll
        for (int k = 0; k < 16; k++) {
            float a[8], b[8];
            *(float4*)&a[0] = *(const float4*)&As[k][tm];
            *(float4*)&a[4] = *(const float4*)&As[k][tm + 4];
            *(float4*)&b[0] = *(const float4*)&Bs[k][tn];
            *(float4*)&b[4] = *(const float4*)&Bs[k][tn + 4];
#pragma unroll
            for (int i = 0; i < 8; i++)
#pragma unroll
                for (int j = 0; j < 8; j++)
                    acc[i][j] = fmaf(a[i], b[j], acc[i][j]);
        }
    }

#pragma unroll
    for (int i = 0; i < 8; i++) {
        const long m = (long)bm * 128 + tm + i;
#pragma unroll
        for (int j = 0; j < 8; j++) {
            const int n = bn * 128 + tn + j;
            float v = acc[i][j];
            if (EPI == 1) v += bias[n];
            if (EPI == 2) v = fast_sigmoid(v) * (float)gateC[m * 256 + n];
            Cout[m * (long)N + n] = (_Float16)v;
        }
    }
}

// ---------------------------------------------------------------------------
// Fused attention: per block = one (p,b) pair (m = p*16+b).
// ---------------------------------------------------------------------------
__global__ __launch_bounds__(256) void attn_k(
    const float* __restrict__ question,  // (Q,B,E) fp32
    const float* __restrict__ vvec,      // (H,) fp32
    const _Float16* __restrict__ Wp,     // (P*B, H) f16
    const _Float16* __restrict__ Wq,     // (Q*B, H) f16
    _Float16* __restrict__ Cc)           // (P*B, E) f16 out
{
    __shared__ float sc[QQ];
    __shared__ float aw[QQ];
    const int tid = threadIdx.x;
    const int blk = blockIdx.x;   // m = p*16 + b
    const int b = blk & 15;
    const int wave = tid >> 6, lane = tid & 63;

    float wp0[4], vv[4];
#pragma unroll
    for (int j = 0; j < 4; j++) {
        wp0[j] = (float)Wp[(long)blk * 256 + lane + 64 * j];
        vv[j] = vvec[lane + 64 * j];
    }
#pragma unroll 2
    for (int qi = 0; qi < 16; qi++) {
        const int q = wave * 16 + qi;
        const _Float16* wqp = Wq + (long)(q * 16 + b) * 256;
        float s = 0.f;
#pragma unroll
        for (int j = 0; j < 4; j++) {
            float x = (float)wqp[lane + 64 * j] + wp0[j];
            s += fast_tanh(x) * vv[j];
        }
#pragma unroll
        for (int off = 32; off; off >>= 1) s += __shfl_xor(s, off, 64);
        if (lane == 0) sc[q] = s;
    }
    __syncthreads();
    if (tid < 64) {
        float s = sc[tid];
        float mx = s;
#pragma unroll
        for (int off = 32; off; off >>= 1) mx = fmaxf(mx, __shfl_xor(mx, off, 64));
        float e = __expf(s - mx);
        float sum = e;
#pragma unroll
        for (int off = 32; off; off >>= 1) sum += __shfl_xor(sum, off, 64);
        aw[tid] = e * __frcp_rn(sum);
    }
    __syncthreads();
    float acc = 0.f;
#pragma unroll 4
    for (int q = 0; q < QQ; q++) {
        acc = fmaf(aw[q], question[(long)(q * 16 + b) * 256 + tid], acc);
    }
    Cc[(long)blk * 256 + tid] = (_Float16)acc;
}

// ---------------------------------------------------------------------------
// GRU scan, v4. 16 blocks (one per batch b), 1024 threads (16 waves, 4/SIMD).
// Identical decomposition to v3 (thread (q,e): quarter-dot of rows
// {e, e+256, e+512} over k in [64q, 64q+64), 96 half2 weight regs), but with
// __launch_bounds__(1024, 4): 4 waves/EU pins the unified register cap at
// 128/wave, which is exactly what a 16-wave block can physically use
// (4 waves x 128 = 512-reg SIMD file). v3's bare launch_bounds(1024) made
// the allocator target 8 waves/EU -> 64 arch VGPRs -> all 96 weight regs
// went to AGPRs, and every fdot2 operand paid a v_accvgpr_read (dur 710us,
// VGPR_Count=64). With the cap at 128 the weights (96) + working set (~25)
// live in true VGPRs: hot loop is 96 back-to-back v_dot2 with no moves.
// gi/out addressing is strength-reduced to loop-carried pointers to keep
// the working set under the 128 cliff.
// ---------------------------------------------------------------------------
__global__ __launch_bounds__(1024, 4) void gru_k(
    const float* __restrict__ whh,    // (768,256) fp32
    const float* __restrict__ bhh,    // (768,) fp32
    const _Float16* __restrict__ gi,  // (P*B, 768) f16 (b_ih folded in)
    float* __restrict__ out)          // (P,B,O) fp32
{
    __shared__ __align__(16) _Float16 hbuf[2][256];
    __shared__ float part[3][3][256];   // [q-1][gate][e]
    const int tid = threadIdx.x;
    const int q = tid >> 8;       // k-slice index 0..3
    const int e = tid & 255;
    const int b = blockIdx.x;
    const int koff = q * 64;

    // Load weight slices: rows e (r-gate), e+256 (z), e+512 (n), cols [koff, koff+64)
    half2_t wr[32], wz[32], wn[32];
    {
        const float* pr = whh + (long)e * 256 + koff;
        const float* pz = whh + (long)(e + 256) * 256 + koff;
        const float* pn = whh + (long)(e + 512) * 256 + koff;
#pragma unroll
        for (int j = 0; j < 16; j++) {
            float4 a = *(const float4*)(pr + 4 * j);
            float4 c = *(const float4*)(pz + 4 * j);
            float4 d = *(const float4*)(pn + 4 * j);
            half2_t t;
            t[0] = (_Float16)a.x; t[1] = (_Float16)a.y; wr[2 * j] = t;
            t[0] = (_Float16)a.z; t[1] = (_Float16)a.w; wr[2 * j + 1] = t;
            t[0] = (_Float16)c.x; t[1] = (_Float16)c.y; wz[2 * j] = t;
            t[0] = (_Float16)c.z; t[1] = (_Float16)c.w; wz[2 * j + 1] = t;
            t[0] = (_Float16)d.x; t[1] = (_Float16)d.y; wn[2 * j] = t;
            t[0] = (_Float16)d.z; t[1] = (_Float16)d.w; wn[2 * j + 1] = t;
        }
    }
    float b_r = 0.f, b_z = 0.f, b_n = 0.f;
    if (q == 0) {
        b_r = bhh[e];
        b_z = bhh[e + 256];
        b_n = bhh[e + 512];
        hbuf[0][e] = (_Float16)0.f;
    }
    float h = 0.f;
    // Loop-carried global pointers (q==0 only uses them, but keeping them
    // uniform-stride avoids per-step 64-bit address rebuilds).
    const _Float16* gip = gi + (long)b * 768 + e;
    float* outp = out + (long)b * 256 + e;
    __syncthreads();

    int cur = 0;
    for (int t = 0; t < PP; t++) {
        // gi prefetch (q==0 only); latency hidden by the matvec + barrier.
        float g0 = 0.f, g1 = 0.f, g2 = 0.f;
        if (q == 0) {
            g0 = (float)gip[0];
            g1 = (float)gip[256];
            g2 = (float)gip[512];
        }
        // Quarter-dot over this thread's 64-wide k-slice of the broadcast h.
        const uint4* hp4 = ((const uint4*)hbuf[cur]) + q * 8;
        float ar = 0.f, az = 0.f, an = 0.f;
#pragma unroll
        for (int j = 0; j < 8; j++) {
            uint4 hp = hp4[j];
            half2_t h0 = __builtin_bit_cast(half2_t, hp.x);
            half2_t h1 = __builtin_bit_cast(half2_t, hp.y);
            half2_t h2 = __builtin_bit_cast(half2_t, hp.z);
            half2_t h3 = __builtin_bit_cast(half2_t, hp.w);
            ar = fdot2f(wr[4 * j + 0], h0, ar);
            ar = fdot2f(wr[4 * j + 1], h1, ar);
            ar = fdot2f(wr[4 * j + 2], h2, ar);
            ar = fdot2f(wr[4 * j + 3], h3, ar);
            az = fdot2f(wz[4 * j + 0], h0, az);
            az = fdot2f(wz[4 * j + 1], h1, az);
            az = fdot2f(wz[4 * j + 2], h2, az);
            az = fdot2f(wz[4 * j + 3], h3, az);
            an = fdot2f(wn[4 * j + 0], h0, an);
            an = fdot2f(wn[4 * j + 1], h1, an);
            an = fdot2f(wn[4 * j + 2], h2, an);
            an = fdot2f(wn[4 * j + 3], h3, an);
        }
        if (q) {
            part[q - 1][0][e] = ar;
            part[q - 1][1][e] = az;
            part[q - 1][2][e] = an;
        }
        __syncthreads();
        if (q == 0) {
            float ghr = ar + part[0][0][e] + part[1][0][e] + part[2][0][e] + b_r;
            float ghz = az + part[0][1][e] + part[1][1][e] + part[2][1][e] + b_z;
            float ghn = an + part[0][2][e] + part[1][2][e] + part[2][2][e] + b_n;
            float r = fast_sigmoid(g0 + ghr);
            float z = fast_sigmoid(g1 + ghz);
            float n = fast_tanh(fmaf(r, ghn, g2));
            h = (1.f - z) * n + z * h;
            *outp = h;
            hbuf[cur ^ 1][e] = (_Float16)h;
        }
        __syncthreads();
        cur ^= 1;
        gip += 16 * 768;
        outp += 16 * 256;
    }
}

// ---------------------------------------------------------------------------
extern "C" void kernel_launch(void* const* d_in, const int* in_sizes, int n_in,
                              void* d_out, int out_size, void* d_ws, size_t ws_size,
                              hipStream_t stream)
{
    const float* passage  = (const float*)d_in[0];   // (512,16,256) fp32
    const float* question = (const float*)d_in[1];   // (64,16,256) fp32
    const float* Wuq      = (const float*)d_in[2];   // (256,256) fp32
    const float* Wup      = (const float*)d_in[3];   // (256,256) fp32
    const float* vvec     = (const float*)d_in[4];   // (1,256) fp32
    const float* Wg       = (const float*)d_in[5];   // (512,512) fp32
    const float* w_ih     = (const float*)d_in[6];   // (768,256) fp32
    const float* w_hh     = (const float*)d_in[7];   // (768,256) fp32
    const float* b_ih     = (const float*)d_in[8];   // (768,) fp32
    const float* b_hh     = (const float*)d_in[9];   // (768,) fp32

    // Workspace layout (all fp16) — total footprint exactly 16 MiB.
    //   [0,      12.0MiB) : gi (8192x768)  — written LAST; overlaps Wq/Wp/c,
    //                        which are all dead by the time gi is produced.
    //       [0,     0.5MiB) : Wq (1024x256)   dead after attn
    //       [0.5,   4.5MiB) : Wp (8192x256)   dead after attn
    //       [4.5,   8.5MiB) : c  (8192x256)   dead after gate GEMM
    //   [12MiB, 16MiB)     : cg (8192x256)    alive until gi GEMM done
    char* ws = (char*)d_ws;
    _Float16* gi_ws = (_Float16*)(ws);
    _Float16* Wq_ws = (_Float16*)(ws);
    _Float16* Wp_ws = (_Float16*)(ws + (512u << 10));
    _Float16* c_ws  = (_Float16*)(ws + (4608u << 10));
    _Float16* cg_ws = (_Float16*)(ws + (12288u << 10));

    // 1) Wq = question @ Wuq^T   (1024 x 256, K=256)
    gemm_k<0, 0><<<dim3(8, 2), 256, 0, stream>>>(question, nullptr, Wuq, nullptr, nullptr,
                                                 Wq_ws, 1024, 256, 256);
    // 2) Wp = passage @ Wup^T    (8192 x 256, K=256)
    gemm_k<0, 0><<<dim3(64, 2), 256, 0, stream>>>(passage, nullptr, Wup, nullptr, nullptr,
                                                  Wp_ws, 8192, 256, 256);
    // 3) attention -> c (8192 x 256)
    attn_k<<<8192, 256, 0, stream>>>(question, vvec, Wp_ws, Wq_ws, c_ws);
    // 4) cg = sigmoid([passage,c] @ Wg[256:512]^T) * c   (8192 x 256, K=512)
    gemm_k<2, 2><<<dim3(64, 2), 256, 0, stream>>>(passage, c_ws, Wg + 256 * 512, nullptr, c_ws,
                                                  cg_ws, 8192, 256, 512);
    // 5) gi = cg @ w_ih^T + b_ih   (8192 x 768, K=256)
    gemm_k<3, 1><<<dim3(64, 6), 256, 0, stream>>>(nullptr, cg_ws, w_ih, b_ih, nullptr,
                                                  gi_ws, 8192, 768, 256);
    // 6) GRU scan -> out (fp32)
    gru_k<<<16, 1024, 0, stream>>>(w_hh, b_hh, gi_ws, (float*)d_out);
}

// Round 3
// 1048.582 us; speedup vs baseline: 1.0103x; 1.0048x over previous
//
#include <hip/hip_runtime.h>
#include <hip/hip_bf16.h>

// Problem dims
#define PP 512
#define QQ 64
#define BB 16
#define EE 256
#define HH 256
#define OO 256

typedef _Float16 half2_t __attribute__((ext_vector_type(2)));

__device__ __forceinline__ void unpack8h(const uint4 r, float* v) {
    const _Float16* s = (const _Float16*)&r;
#pragma unroll
    for (int i = 0; i < 8; i++) v[i] = (float)s[i];
}
__device__ __forceinline__ float fast_tanh(float x) {
    x = fminf(fmaxf(x, -15.f), 15.f);
    float e = __expf(2.f * x);
    return (e - 1.f) * __frcp_rn(e + 1.f);
}
__device__ __forceinline__ float fast_sigmoid(float x) {
    x = fminf(fmaxf(x, -30.f), 30.f);
    return __frcp_rn(1.f + __expf(-x));
}
__device__ __forceinline__ float fdot2f(half2_t a, half2_t b, float c) {
#if defined(__has_builtin)
#if __has_builtin(__builtin_amdgcn_fdot2)
    return __builtin_amdgcn_fdot2(a, b, c, false);
#else
    return (float)a[0] * (float)b[0] + (float)a[1] * (float)b[1] + c;
#endif
#else
    return (float)a[0] * (float)b[0] + (float)a[1] * (float)b[1] + c;
#endif
}

// ---------------------------------------------------------------------------
// Generic tiled GEMM: C[m,n] = epilogue( sum_k A[m,k] * B[n,k] )
// Tile 128x128, K-chunk 16, 256 threads, 8x8 micro-tile, fp32 accumulate.
// Output fp16. B (weight) is fp32, row n = B[n, 0:K].
// AMODE: 0 = A fp32 (row stride K)
//        2 = A concat: k<256 -> Af32 (fp32, row stride 256), k>=256 -> Ah (f16, row stride 256)
//        3 = A f16 (row stride K)
// EPI:   0 = none
//        1 = + bias[n] (fp32)
//        2 = sigmoid(acc) * gateC[m*256+n] (f16)   [only used with N=256]
// ---------------------------------------------------------------------------
template <int AMODE, int EPI>
__global__ __launch_bounds__(256) void gemm_k(
    const float* __restrict__ Af32,
    const _Float16* __restrict__ Ah,
    const float* __restrict__ Bw,
    const float* __restrict__ bias,
    const _Float16* __restrict__ gateC,
    _Float16* __restrict__ Cout, int M, int N, int K)
{
    __shared__ float As[16][128];
    __shared__ float Bs[16][128];
    const int tid = threadIdx.x;
    const int bm = blockIdx.x, bn = blockIdx.y;
    const int ra = tid >> 1;          // 0..127 : row within tile for staging
    const int ka = (tid & 1) * 8;     // 0 or 8 : k-offset within chunk
    const int tm = (tid >> 4) * 8;    // micro-tile row base
    const int tn = (tid & 15) * 8;    // micro-tile col base

    float acc[8][8];
#pragma unroll
    for (int i = 0; i < 8; i++)
#pragma unroll
        for (int j = 0; j < 8; j++) acc[i][j] = 0.f;

    const long arow = (long)bm * 128 + ra;
    const long brow = (long)bn * 128 + ra;

    for (int k0 = 0; k0 < K; k0 += 16) {
        float av[8], bv[8];
        const int kk = k0 + ka;
        if (AMODE == 0) {
            const float* p = Af32 + arow * K + kk;
            float4 r0 = *(const float4*)(p);
            float4 r1 = *(const float4*)(p + 4);
            av[0] = r0.x; av[1] = r0.y; av[2] = r0.z; av[3] = r0.w;
            av[4] = r1.x; av[5] = r1.y; av[6] = r1.z; av[7] = r1.w;
        } else if (AMODE == 3) {
            uint4 r = *(const uint4*)(Ah + arow * K + kk);
            unpack8h(r, av);
        } else { // AMODE == 2
            if (kk < 256) {
                const float* p = Af32 + arow * 256 + kk;
                float4 r0 = *(const float4*)(p);
                float4 r1 = *(const float4*)(p + 4);
                av[0] = r0.x; av[1] = r0.y; av[2] = r0.z; av[3] = r0.w;
                av[4] = r1.x; av[5] = r1.y; av[6] = r1.z; av[7] = r1.w;
            } else {
                uint4 r = *(const uint4*)(Ah + arow * 256 + (kk - 256));
                unpack8h(r, av);
            }
        }
        {
            const float* p = Bw + brow * K + kk;
            float4 r0 = *(const float4*)(p);
            float4 r1 = *(const float4*)(p + 4);
            bv[0] = r0.x; bv[1] = r0.y; bv[2] = r0.z; bv[3] = r0.w;
            bv[4] = r1.x; bv[5] = r1.y; bv[6] = r1.z; bv[7] = r1.w;
        }
        __syncthreads();
#pragma unroll
        for (int i = 0; i < 8; i++) { As[ka + i][ra] = av[i]; Bs[ka + i][ra] = bv[i]; }
        __syncthreads();
#pragma unroll
        for (int k = 0; k < 16; k++) {
            float a[8], b[8];
            *(float4*)&a[0] = *(const float4*)&As[k][tm];
            *(float4*)&a[4] = *(const float4*)&As[k][tm + 4];
            *(float4*)&b[0] = *(const float4*)&Bs[k][tn];
            *(float4*)&b[4] = *(const float4*)&Bs[k][tn + 4];
#pragma unroll
            for (int i = 0; i < 8; i++)
#pragma unroll
                for (int j = 0; j < 8; j++)
                    acc[i][j] = fmaf(a[i], b[j], acc[i][j]);
        }
    }

#pragma unroll
    for (int i = 0; i < 8; i++) {
        const long m = (long)bm * 128 + tm + i;
#pragma unroll
        for (int j = 0; j < 8; j++) {
            const int n = bn * 128 + tn + j;
            float v = acc[i][j];
            if (EPI == 1) v += bias[n];
            if (EPI == 2) v = fast_sigmoid(v) * (float)gateC[m * 256 + n];
            Cout[m * (long)N + n] = (_Float16)v;
        }
    }
}

// ---------------------------------------------------------------------------
// Fused attention: per block = one (p,b) pair (m = p*16+b).
// ---------------------------------------------------------------------------
__global__ __launch_bounds__(256) void attn_k(
    const float* __restrict__ question,  // (Q,B,E) fp32
    const float* __restrict__ vvec,      // (H,) fp32
    const _Float16* __restrict__ Wp,     // (P*B, H) f16
    const _Float16* __restrict__ Wq,     // (Q*B, H) f16
    _Float16* __restrict__ Cc)           // (P*B, E) f16 out
{
    __shared__ float sc[QQ];
    __shared__ float aw[QQ];
    const int tid = threadIdx.x;
    const int blk = blockIdx.x;   // m = p*16 + b
    const int b = blk & 15;
    const int wave = tid >> 6, lane = tid & 63;

    float wp0[4], vv[4];
#pragma unroll
    for (int j = 0; j < 4; j++) {
        wp0[j] = (float)Wp[(long)blk * 256 + lane + 64 * j];
        vv[j] = vvec[lane + 64 * j];
    }
#pragma unroll 2
    for (int qi = 0; qi < 16; qi++) {
        const int q = wave * 16 + qi;
        const _Float16* wqp = Wq + (long)(q * 16 + b) * 256;
        float s = 0.f;
#pragma unroll
        for (int j = 0; j < 4; j++) {
            float x = (float)wqp[lane + 64 * j] + wp0[j];
            s += fast_tanh(x) * vv[j];
        }
#pragma unroll
        for (int off = 32; off; off >>= 1) s += __shfl_xor(s, off, 64);
        if (lane == 0) sc[q] = s;
    }
    __syncthreads();
    if (tid < 64) {
        float s = sc[tid];
        float mx = s;
#pragma unroll
        for (int off = 32; off; off >>= 1) mx = fmaxf(mx, __shfl_xor(mx, off, 64));
        float e = __expf(s - mx);
        float sum = e;
#pragma unroll
        for (int off = 32; off; off >>= 1) sum += __shfl_xor(sum, off, 64);
        aw[tid] = e * __frcp_rn(sum);
    }
    __syncthreads();
    float acc = 0.f;
#pragma unroll 4
    for (int q = 0; q < QQ; q++) {
        acc = fmaf(aw[q], question[(long)(q * 16 + b) * 256 + tid], acc);
    }
    Cc[(long)blk * 256 + tid] = (_Float16)acc;
}

// ---------------------------------------------------------------------------
// GRU scan, v5. 16 blocks (one per batch b), 1024 threads (16 waves).
// Same decomposition as v3/v4: thread (q,e), quarter-dot of rows
// {e, e+256, e+512} over k in [64q, 64q+64), 96 half2 weight regs.
//
// v4 post-mortem: __launch_bounds__(1024, 4) sets only the MIN waves/EU
// (i.e. a 128-reg upper bound); the allocator's occupancy HEURISTIC still
// targeted 8 waves/EU (2 blocks/CU fits the 10KB LDS) -> 64 arch VGPRs ->
// all 96 weight regs in AGPRs -> one v_accvgpr_read per fdot2 operand.
// Measured: VGPR_Count=64, ~1990 VALU cyc/step = 4 waves/SIMD x
// (96 dot2 + 96 accvgpr_read + ~40 ovh) x 2cyc. The fix is to clamp the
// occupancy TARGET itself: amdgpu_waves_per_eu(4,4) makes 4 waves/EU both
// the floor and the ceiling, so the allocator can use the full 128-reg
// budget (4 waves x 128 = 512-reg SIMD file) at zero modeled cost.
// Weights (96) + working set (~25) then live in true VGPRs; the hot loop
// is 96 back-to-back v_dot2 with no cross-file moves.
// ---------------------------------------------------------------------------
__global__ __launch_bounds__(1024)
__attribute__((amdgpu_waves_per_eu(4, 4)))
void gru_k(
    const float* __restrict__ whh,    // (768,256) fp32
    const float* __restrict__ bhh,    // (768,) fp32
    const _Float16* __restrict__ gi,  // (P*B, 768) f16 (b_ih folded in)
    float* __restrict__ out)          // (P,B,O) fp32
{
    __shared__ __align__(16) _Float16 hbuf[2][256];
    __shared__ float part[3][3][256];   // [q-1][gate][e]
    const int tid = threadIdx.x;
    const int q = tid >> 8;       // k-slice index 0..3
    const int e = tid & 255;
    const int b = blockIdx.x;
    const int koff = q * 64;

    // Load weight slices: rows e (r-gate), e+256 (z), e+512 (n), cols [koff, koff+64)
    half2_t wr[32], wz[32], wn[32];
    {
        const float* pr = whh + (long)e * 256 + koff;
        const float* pz = whh + (long)(e + 256) * 256 + koff;
        const float* pn = whh + (long)(e + 512) * 256 + koff;
#pragma unroll
        for (int j = 0; j < 16; j++) {
            float4 a = *(const float4*)(pr + 4 * j);
            float4 c = *(const float4*)(pz + 4 * j);
            float4 d = *(const float4*)(pn + 4 * j);
            half2_t t;
            t[0] = (_Float16)a.x; t[1] = (_Float16)a.y; wr[2 * j] = t;
            t[0] = (_Float16)a.z; t[1] = (_Float16)a.w; wr[2 * j + 1] = t;
            t[0] = (_Float16)c.x; t[1] = (_Float16)c.y; wz[2 * j] = t;
            t[0] = (_Float16)c.z; t[1] = (_Float16)c.w; wz[2 * j + 1] = t;
            t[0] = (_Float16)d.x; t[1] = (_Float16)d.y; wn[2 * j] = t;
            t[0] = (_Float16)d.z; t[1] = (_Float16)d.w; wn[2 * j + 1] = t;
        }
    }
    float b_r = 0.f, b_z = 0.f, b_n = 0.f;
    if (q == 0) {
        b_r = bhh[e];
        b_z = bhh[e + 256];
        b_n = bhh[e + 512];
        hbuf[0][e] = (_Float16)0.f;
    }
    float h = 0.f;
    // Loop-carried global pointers (q==0 only uses them, but keeping them
    // uniform-stride avoids per-step 64-bit address rebuilds).
    const _Float16* gip = gi + (long)b * 768 + e;
    float* outp = out + (long)b * 256 + e;
    __syncthreads();

    int cur = 0;
    for (int t = 0; t < PP; t++) {
        // gi prefetch (q==0 only); latency hidden by the matvec + barrier.
        float g0 = 0.f, g1 = 0.f, g2 = 0.f;
        if (q == 0) {
            g0 = (float)gip[0];
            g1 = (float)gip[256];
            g2 = (float)gip[512];
        }
        // Quarter-dot over this thread's 64-wide k-slice of the broadcast h.
        const uint4* hp4 = ((const uint4*)hbuf[cur]) + q * 8;
        float ar = 0.f, az = 0.f, an = 0.f;
#pragma unroll
        for (int j = 0; j < 8; j++) {
            uint4 hp = hp4[j];
            half2_t h0 = __builtin_bit_cast(half2_t, hp.x);
            half2_t h1 = __builtin_bit_cast(half2_t, hp.y);
            half2_t h2 = __builtin_bit_cast(half2_t, hp.z);
            half2_t h3 = __builtin_bit_cast(half2_t, hp.w);
            ar = fdot2f(wr[4 * j + 0], h0, ar);
            ar = fdot2f(wr[4 * j + 1], h1, ar);
            ar = fdot2f(wr[4 * j + 2], h2, ar);
            ar = fdot2f(wr[4 * j + 3], h3, ar);
            az = fdot2f(wz[4 * j + 0], h0, az);
            az = fdot2f(wz[4 * j + 1], h1, az);
            az = fdot2f(wz[4 * j + 2], h2, az);
            az = fdot2f(wz[4 * j + 3], h3, az);
            an = fdot2f(wn[4 * j + 0], h0, an);
            an = fdot2f(wn[4 * j + 1], h1, an);
            an = fdot2f(wn[4 * j + 2], h2, an);
            an = fdot2f(wn[4 * j + 3], h3, an);
        }
        if (q) {
            part[q - 1][0][e] = ar;
            part[q - 1][1][e] = az;
            part[q - 1][2][e] = an;
        }
        __syncthreads();
        if (q == 0) {
            float ghr = ar + part[0][0][e] + part[1][0][e] + part[2][0][e] + b_r;
            float ghz = az + part[0][1][e] + part[1][1][e] + part[2][1][e] + b_z;
            float ghn = an + part[0][2][e] + part[1][2][e] + part[2][2][e] + b_n;
            float r = fast_sigmoid(g0 + ghr);
            float z = fast_sigmoid(g1 + ghz);
            float n = fast_tanh(fmaf(r, ghn, g2));
            h = (1.f - z) * n + z * h;
            *outp = h;
            hbuf[cur ^ 1][e] = (_Float16)h;
        }
        __syncthreads();
        cur ^= 1;
        gip += 16 * 768;
        outp += 16 * 256;
    }
}

// ---------------------------------------------------------------------------
extern "C" void kernel_launch(void* const* d_in, const int* in_sizes, int n_in,
                              void* d_out, int out_size, void* d_ws, size_t ws_size,
                              hipStream_t stream)
{
    const float* passage  = (const float*)d_in[0];   // (512,16,256) fp32
    const float* question = (const float*)d_in[1];   // (64,16,256) fp32
    const float* Wuq      = (const float*)d_in[2];   // (256,256) fp32
    const float* Wup      = (const float*)d_in[3];   // (256,256) fp32
    const float* vvec     = (const float*)d_in[4];   // (1,256) fp32
    const float* Wg       = (const float*)d_in[5];   // (512,512) fp32
    const float* w_ih     = (const float*)d_in[6];   // (768,256) fp32
    const float* w_hh     = (const float*)d_in[7];   // (768,256) fp32
    const float* b_ih     = (const float*)d_in[8];   // (768,) fp32
    const float* b_hh     = (const float*)d_in[9];   // (768,) fp32

    // Workspace layout (all fp16) — total footprint exactly 16 MiB.
    //   [0,      12.0MiB) : gi (8192x768)  — written LAST; overlaps Wq/Wp/c,
    //                        which are all dead by the time gi is produced.
    //       [0,     0.5MiB) : Wq (1024x256)   dead after attn
    //       [0.5,   4.5MiB) : Wp (8192x256)   dead after attn
    //       [4.5,   8.5MiB) : c  (8192x256)   dead after gate GEMM
    //   [12MiB, 16MiB)     : cg (8192x256)    alive until gi GEMM done
    char* ws = (char*)d_ws;
    _Float16* gi_ws = (_Float16*)(ws);
    _Float16* Wq_ws = (_Float16*)(ws);
    _Float16* Wp_ws = (_Float16*)(ws + (512u << 10));
    _Float16* c_ws  = (_Float16*)(ws + (4608u << 10));
    _Float16* cg_ws = (_Float16*)(ws + (12288u << 10));

    // 1) Wq = question @ Wuq^T   (1024 x 256, K=256)
    gemm_k<0, 0><<<dim3(8, 2), 256, 0, stream>>>(question, nullptr, Wuq, nullptr, nullptr,
                                                 Wq_ws, 1024, 256, 256);
    // 2) Wp = passage @ Wup^T    (8192 x 256, K=256)
    gemm_k<0, 0><<<dim3(64, 2), 256, 0, stream>>>(passage, nullptr, Wup, nullptr, nullptr,
                                                  Wp_ws, 8192, 256, 256);
    // 3) attention -> c (8192 x 256)
    attn_k<<<8192, 256, 0, stream>>>(question, vvec, Wp_ws, Wq_ws, c_ws);
    // 4) cg = sigmoid([passage,c] @ Wg[256:512]^T) * c   (8192 x 256, K=512)
    gemm_k<2, 2><<<dim3(64, 2), 256, 0, stream>>>(passage, c_ws, Wg + 256 * 512, nullptr, c_ws,
                                                  cg_ws, 8192, 256, 512);
    // 5) gi = cg @ w_ih^T + b_ih   (8192 x 768, K=256)
    gemm_k<3, 1><<<dim3(64, 6), 256, 0, stream>>>(nullptr, cg_ws, w_ih, b_ih, nullptr,
                                                  gi_ws, 8192, 768, 256);
    // 6) GRU scan -> out (fp32)
    gru_k<<<16, 1024, 0, stream>>>(w_hh, b_hh, gi_ws, (float*)d_out);
}

// Round 4
// 972.090 us; speedup vs baseline: 1.0898x; 1.0787x over previous
//
#include <hip/hip_runtime.h>
#include <hip/hip_bf16.h>

// Problem dims
#define PP 512
#define QQ 64
#define BB 16
#define EE 256
#define HH 256
#define OO 256

typedef _Float16 half2_t __attribute__((ext_vector_type(2)));
typedef _Float16 f16x8 __attribute__((ext_vector_type(8)));
typedef float f32x4 __attribute__((ext_vector_type(4)));

__device__ __forceinline__ void unpack8h(const uint4 r, float* v) {
    const _Float16* s = (const _Float16*)&r;
#pragma unroll
    for (int i = 0; i < 8; i++) v[i] = (float)s[i];
}
__device__ __forceinline__ float fast_tanh(float x) {
    x = fminf(fmaxf(x, -15.f), 15.f);
    float e = __expf(2.f * x);
    return (e - 1.f) * __frcp_rn(e + 1.f);
}
__device__ __forceinline__ float fast_sigmoid(float x) {
    x = fminf(fmaxf(x, -30.f), 30.f);
    return __frcp_rn(1.f + __expf(-x));
}

// ---------------------------------------------------------------------------
// Generic tiled GEMM: C[m,n] = epilogue( sum_k A[m,k] * B[n,k] )
// Tile 128x128, K-chunk 16, 256 threads, 8x8 micro-tile, fp32 accumulate.
// Output fp16. B (weight) is fp32, row n = B[n, 0:K].
// AMODE: 0 = A fp32 (row stride K)
//        2 = A concat: k<256 -> Af32 (fp32, row stride 256), k>=256 -> Ah (f16, row stride 256)
//        3 = A f16 (row stride K)
// EPI:   0 = none
//        1 = + bias[n] (fp32)
//        2 = sigmoid(acc) * gateC[m*256+n] (f16)   [only used with N=256]
// ---------------------------------------------------------------------------
template <int AMODE, int EPI>
__global__ __launch_bounds__(256) void gemm_k(
    const float* __restrict__ Af32,
    const _Float16* __restrict__ Ah,
    const float* __restrict__ Bw,
    const float* __restrict__ bias,
    const _Float16* __restrict__ gateC,
    _Float16* __restrict__ Cout, int M, int N, int K)
{
    __shared__ float As[16][128];
    __shared__ float Bs[16][128];
    const int tid = threadIdx.x;
    const int bm = blockIdx.x, bn = blockIdx.y;
    const int ra = tid >> 1;          // 0..127 : row within tile for staging
    const int ka = (tid & 1) * 8;     // 0 or 8 : k-offset within chunk
    const int tm = (tid >> 4) * 8;    // micro-tile row base
    const int tn = (tid & 15) * 8;    // micro-tile col base

    float acc[8][8];
#pragma unroll
    for (int i = 0; i < 8; i++)
#pragma unroll
        for (int j = 0; j < 8; j++) acc[i][j] = 0.f;

    const long arow = (long)bm * 128 + ra;
    const long brow = (long)bn * 128 + ra;

    for (int k0 = 0; k0 < K; k0 += 16) {
        float av[8], bv[8];
        const int kk = k0 + ka;
        if (AMODE == 0) {
            const float* p = Af32 + arow * K + kk;
            float4 r0 = *(const float4*)(p);
            float4 r1 = *(const float4*)(p + 4);
            av[0] = r0.x; av[1] = r0.y; av[2] = r0.z; av[3] = r0.w;
            av[4] = r1.x; av[5] = r1.y; av[6] = r1.z; av[7] = r1.w;
        } else if (AMODE == 3) {
            uint4 r = *(const uint4*)(Ah + arow * K + kk);
            unpack8h(r, av);
        } else { // AMODE == 2
            if (kk < 256) {
                const float* p = Af32 + arow * 256 + kk;
                float4 r0 = *(const float4*)(p);
                float4 r1 = *(const float4*)(p + 4);
                av[0] = r0.x; av[1] = r0.y; av[2] = r0.z; av[3] = r0.w;
                av[4] = r1.x; av[5] = r1.y; av[6] = r1.z; av[7] = r1.w;
            } else {
                uint4 r = *(const uint4*)(Ah + arow * 256 + (kk - 256));
                unpack8h(r, av);
            }
        }
        {
            const float* p = Bw + brow * K + kk;
            float4 r0 = *(const float4*)(p);
            float4 r1 = *(const float4*)(p + 4);
            bv[0] = r0.x; bv[1] = r0.y; bv[2] = r0.z; bv[3] = r0.w;
            bv[4] = r1.x; bv[5] = r1.y; bv[6] = r1.z; bv[7] = r1.w;
        }
        __syncthreads();
#pragma unroll
        for (int i = 0; i < 8; i++) { As[ka + i][ra] = av[i]; Bs[ka + i][ra] = bv[i]; }
        __syncthreads();
#pragma unroll
        for (int k = 0; k < 16; k++) {
            float a[8], b[8];
            *(float4*)&a[0] = *(const float4*)&As[k][tm];
            *(float4*)&a[4] = *(const float4*)&As[k][tm + 4];
            *(float4*)&b[0] = *(const float4*)&Bs[k][tn];
            *(float4*)&b[4] = *(const float4*)&Bs[k][tn + 4];
#pragma unroll
            for (int i = 0; i < 8; i++)
#pragma unroll
                for (int j = 0; j < 8; j++)
                    acc[i][j] = fmaf(a[i], b[j], acc[i][j]);
        }
    }

#pragma unroll
    for (int i = 0; i < 8; i++) {
        const long m = (long)bm * 128 + tm + i;
#pragma unroll
        for (int j = 0; j < 8; j++) {
            const int n = bn * 128 + tn + j;
            float v = acc[i][j];
            if (EPI == 1) v += bias[n];
            if (EPI == 2) v = fast_sigmoid(v) * (float)gateC[m * 256 + n];
            Cout[m * (long)N + n] = (_Float16)v;
        }
    }
}

// ---------------------------------------------------------------------------
// Fused attention: per block = one (p,b) pair (m = p*16+b).
// ---------------------------------------------------------------------------
__global__ __launch_bounds__(256) void attn_k(
    const float* __restrict__ question,  // (Q,B,E) fp32
    const float* __restrict__ vvec,      // (H,) fp32
    const _Float16* __restrict__ Wp,     // (P*B, H) f16
    const _Float16* __restrict__ Wq,     // (Q*B, H) f16
    _Float16* __restrict__ Cc)           // (P*B, E) f16 out
{
    __shared__ float sc[QQ];
    __shared__ float aw[QQ];
    const int tid = threadIdx.x;
    const int blk = blockIdx.x;   // m = p*16 + b
    const int b = blk & 15;
    const int wave = tid >> 6, lane = tid & 63;

    float wp0[4], vv[4];
#pragma unroll
    for (int j = 0; j < 4; j++) {
        wp0[j] = (float)Wp[(long)blk * 256 + lane + 64 * j];
        vv[j] = vvec[lane + 64 * j];
    }
#pragma unroll 2
    for (int qi = 0; qi < 16; qi++) {
        const int q = wave * 16 + qi;
        const _Float16* wqp = Wq + (long)(q * 16 + b) * 256;
        float s = 0.f;
#pragma unroll
        for (int j = 0; j < 4; j++) {
            float x = (float)wqp[lane + 64 * j] + wp0[j];
            s += fast_tanh(x) * vv[j];
        }
#pragma unroll
        for (int off = 32; off; off >>= 1) s += __shfl_xor(s, off, 64);
        if (lane == 0) sc[q] = s;
    }
    __syncthreads();
    if (tid < 64) {
        float s = sc[tid];
        float mx = s;
#pragma unroll
        for (int off = 32; off; off >>= 1) mx = fmaxf(mx, __shfl_xor(mx, off, 64));
        float e = __expf(s - mx);
        float sum = e;
#pragma unroll
        for (int off = 32; off; off >>= 1) sum += __shfl_xor(sum, off, 64);
        aw[tid] = e * __frcp_rn(sum);
    }
    __syncthreads();
    float acc = 0.f;
#pragma unroll 4
    for (int q = 0; q < QQ; q++) {
        acc = fmaf(aw[q], question[(long)(q * 16 + b) * 256 + tid], acc);
    }
    Cc[(long)blk * 256 + tid] = (_Float16)acc;
}

// ---------------------------------------------------------------------------
// GRU scan, v6: MFMA formulation. 16 blocks (one per batch), 512 threads
// (8 waves, 2/SIMD via waves_per_eu(2,2) -> 256 unified regs/wave).
//
// Why MFMA: rounds 0-3 proved the allocator always splits the unified file
// and parks long-lived weights in AGPRs, which the VALU (v_dot2) cannot
// read -- every weight use paid a v_accvgpr_read. MFMA reads A/B operands
// from EITHER file, so the AGPR placement becomes free.
//
// Decomposition: gh(768) = h(256) @ w_hh^T as 16x16x32 MFMAs, M-row 0 = the
// batch's h, rows 1-15 zeroed (masked A). Wave w owns n-cols [32w, 32w+32)
// of each gate = 6 n-tiles; B-fragments = 6 tiles x 8 ksteps x 4 regs =
// 192 regs held in AGPRs across the whole scan. Per step per wave:
// 8 A-frag LDS reads (same addr within each 16-lane group -> broadcast,
// conflict-free) + 48 MFMA. C/D layout (verified m89): col=lane&15,
// row=(lane>>4)*4+reg -> row 0 lands in lanes 0-15, reg 0. Those publish
// gh to LDS; after barrier 1, threads 0-255 (one e-column each, spread over
// all 4 SIMDs) apply the gate nonlinearities, write h (f16) back to the
// single h-broadcast buffer, write out; barrier 2 closes the step.
// Note: any k-order uncertainty in the fragment layout cancels because A
// and B are packed with the identical assumed k order.
// ---------------------------------------------------------------------------
__global__ __launch_bounds__(512)
__attribute__((amdgpu_waves_per_eu(2, 2)))
void gru_k(
    const float* __restrict__ whh,    // (768,256) fp32
    const float* __restrict__ bhh,    // (768,) fp32
    const _Float16* __restrict__ gi,  // (P*B, 768) f16 (b_ih folded in)
    float* __restrict__ out)          // (P,B,O) fp32
{
    __shared__ __align__(16) _Float16 hlds[256];   // h broadcast (row 0 of A)
    __shared__ float ghlds[3][256];                // gate pre-activations
    const int tid = threadIdx.x;
    const int w = tid >> 6;        // wave 0..7
    const int lane = tid & 63;
    const int b = blockIdx.x;      // batch

    // ---- stage weights into per-wave B-fragments (AGPR-resident) ----
    // B[k][n] = w_hh[nbase+n][k]; lane holds n = lane&15,
    // k = kk*32 + 8*(lane>>4) + [0..8)  (same k-order as A packing).
    f16x8 bf[3][2][8];
#pragma unroll
    for (int g = 0; g < 3; g++)
#pragma unroll
        for (int c = 0; c < 2; c++) {
            const int n0 = g * 256 + 32 * w + 16 * c + (lane & 15);
            const float* wp = whh + (long)n0 * 256 + 8 * (lane >> 4);
#pragma unroll
            for (int kk = 0; kk < 8; kk++) {
                float4 r0 = *(const float4*)(wp + kk * 32);
                float4 r1 = *(const float4*)(wp + kk * 32 + 4);
                f16x8 t;
                t[0] = (_Float16)r0.x; t[1] = (_Float16)r0.y;
                t[2] = (_Float16)r0.z; t[3] = (_Float16)r0.w;
                t[4] = (_Float16)r1.x; t[5] = (_Float16)r1.y;
                t[6] = (_Float16)r1.z; t[7] = (_Float16)r1.w;
                bf[g][c][kk] = t;
            }
        }

    // ---- per-thread state for the epilogue owners (threads 0..255) ----
    float h = 0.f, bhr = 0.f, bhz = 0.f, bhn = 0.f;
    _Float16 gr = (_Float16)0.f, gz = (_Float16)0.f, gn = (_Float16)0.f;
    const _Float16* gip = gi;
    float* outp = out;
    if (tid < 256) {
        hlds[tid] = (_Float16)0.f;
        bhr = bhh[tid]; bhz = bhh[tid + 256]; bhn = bhh[tid + 512];
        gip = gi + (long)b * 768 + tid;
        gr = gip[0]; gz = gip[256]; gn = gip[512];
        outp = out + (long)b * 256 + tid;
    }
    __syncthreads();

    // A-frag source: all lanes in a 16-lane group read the SAME 16B of h
    // (broadcast); non-row-0 lanes mask their copy to zero (4 v_and).
    const unsigned msk = ((lane & 15) == 0) ? 0xFFFFFFFFu : 0u;
    const _Float16* hb = hlds + 8 * (lane >> 4);

    for (int t = 0; t < PP; t++) {
        // Prefetch next step's gi (latency hidden under this step's MFMA).
        _Float16 gr2 = (_Float16)0.f, gz2 = (_Float16)0.f, gn2 = (_Float16)0.f;
        if (tid < 256) {
            const _Float16* gq = gip + 16 * 768;
            gr2 = gq[0]; gz2 = gq[256]; gn2 = gq[512];
        }

        // ---- matvec: 48 MFMA per wave ----
        f32x4 a00 = {0.f, 0.f, 0.f, 0.f}, a01 = {0.f, 0.f, 0.f, 0.f};
        f32x4 a10 = {0.f, 0.f, 0.f, 0.f}, a11 = {0.f, 0.f, 0.f, 0.f};
        f32x4 a20 = {0.f, 0.f, 0.f, 0.f}, a21 = {0.f, 0.f, 0.f, 0.f};
#pragma unroll
        for (int kk = 0; kk < 8; kk++) {
            uint4 ra = *(const uint4*)(hb + kk * 32);
            ra.x &= msk; ra.y &= msk; ra.z &= msk; ra.w &= msk;
            f16x8 a = __builtin_bit_cast(f16x8, ra);
            a00 = __builtin_amdgcn_mfma_f32_16x16x32_f16(a, bf[0][0][kk], a00, 0, 0, 0);
            a01 = __builtin_amdgcn_mfma_f32_16x16x32_f16(a, bf[0][1][kk], a01, 0, 0, 0);
            a10 = __builtin_amdgcn_mfma_f32_16x16x32_f16(a, bf[1][0][kk], a10, 0, 0, 0);
            a11 = __builtin_amdgcn_mfma_f32_16x16x32_f16(a, bf[1][1][kk], a11, 0, 0, 0);
            a20 = __builtin_amdgcn_mfma_f32_16x16x32_f16(a, bf[2][0][kk], a20, 0, 0, 0);
            a21 = __builtin_amdgcn_mfma_f32_16x16x32_f16(a, bf[2][1][kk], a21, 0, 0, 0);
        }
        // Row 0 of C lives in lanes 0..15, reg 0 (col = lane&15).
        if (lane < 16) {
            const int e0 = 32 * w + lane;
            ghlds[0][e0] = a00[0]; ghlds[0][e0 + 16] = a01[0];
            ghlds[1][e0] = a10[0]; ghlds[1][e0 + 16] = a11[0];
            ghlds[2][e0] = a20[0]; ghlds[2][e0 + 16] = a21[0];
        }
        __syncthreads();

        // ---- gates: one e-column per thread, spread over all SIMDs ----
        if (tid < 256) {
            float ghr = ghlds[0][tid] + bhr;
            float ghz = ghlds[1][tid] + bhz;
            float ghn = ghlds[2][tid] + bhn;
            float r = fast_sigmoid((float)gr + ghr);
            float z = fast_sigmoid((float)gz + ghz);
            float n = fast_tanh(fmaf(r, ghn, (float)gn));
            h = (1.f - z) * n + z * h;
            *outp = h;
            hlds[tid] = (_Float16)h;
            gr = gr2; gz = gz2; gn = gn2;
            gip += 16 * 768;
            outp += 16 * 256;
        }
        __syncthreads();
    }
}

// ---------------------------------------------------------------------------
extern "C" void kernel_launch(void* const* d_in, const int* in_sizes, int n_in,
                              void* d_out, int out_size, void* d_ws, size_t ws_size,
                              hipStream_t stream)
{
    const float* passage  = (const float*)d_in[0];   // (512,16,256) fp32
    const float* question = (const float*)d_in[1];   // (64,16,256) fp32
    const float* Wuq      = (const float*)d_in[2];   // (256,256) fp32
    const float* Wup      = (const float*)d_in[3];   // (256,256) fp32
    const float* vvec     = (const float*)d_in[4];   // (1,256) fp32
    const float* Wg       = (const float*)d_in[5];   // (512,512) fp32
    const float* w_ih     = (const float*)d_in[6];   // (768,256) fp32
    const float* w_hh     = (const float*)d_in[7];   // (768,256) fp32
    const float* b_ih     = (const float*)d_in[8];   // (768,) fp32
    const float* b_hh     = (const float*)d_in[9];   // (768,) fp32

    // Workspace layout (all fp16) — total footprint exactly 16 MiB.
    //   [0,      12.0MiB) : gi (8192x768)  — written LAST; overlaps Wq/Wp/c,
    //                        which are all dead by the time gi is produced.
    //       [0,     0.5MiB) : Wq (1024x256)   dead after attn
    //       [0.5,   4.5MiB) : Wp (8192x256)   dead after attn
    //       [4.5,   8.5MiB) : c  (8192x256)   dead after gate GEMM
    //   [12MiB, 16MiB)     : cg (8192x256)    alive until gi GEMM done
    char* ws = (char*)d_ws;
    _Float16* gi_ws = (_Float16*)(ws);
    _Float16* Wq_ws = (_Float16*)(ws);
    _Float16* Wp_ws = (_Float16*)(ws + (512u << 10));
    _Float16* c_ws  = (_Float16*)(ws + (4608u << 10));
    _Float16* cg_ws = (_Float16*)(ws + (12288u << 10));

    // 1) Wq = question @ Wuq^T   (1024 x 256, K=256)
    gemm_k<0, 0><<<dim3(8, 2), 256, 0, stream>>>(question, nullptr, Wuq, nullptr, nullptr,
                                                 Wq_ws, 1024, 256, 256);
    // 2) Wp = passage @ Wup^T    (8192 x 256, K=256)
    gemm_k<0, 0><<<dim3(64, 2), 256, 0, stream>>>(passage, nullptr, Wup, nullptr, nullptr,
                                                  Wp_ws, 8192, 256, 256);
    // 3) attention -> c (8192 x 256)
    attn_k<<<8192, 256, 0, stream>>>(question, vvec, Wp_ws, Wq_ws, c_ws);
    // 4) cg = sigmoid([passage,c] @ Wg[256:512]^T) * c   (8192 x 256, K=512)
    gemm_k<2, 2><<<dim3(64, 2), 256, 0, stream>>>(passage, c_ws, Wg + 256 * 512, nullptr, c_ws,
                                                  cg_ws, 8192, 256, 512);
    // 5) gi = cg @ w_ih^T + b_ih   (8192 x 768, K=256)
    gemm_k<3, 1><<<dim3(64, 6), 256, 0, stream>>>(nullptr, cg_ws, w_ih, b_ih, nullptr,
                                                  gi_ws, 8192, 768, 256);
    // 6) GRU scan -> out (fp32)
    gru_k<<<16, 512, 0, stream>>>(w_hh, b_hh, gi_ws, (float*)d_out);
}